// Round 6
// baseline (317.158 us; speedup 1.0000x reference)
//
#include <hip/hip_runtime.h>
#include <stdint.h>

#define TOL 1e-2f
#define WPB 4
// ws layout: [0..128): 8 hashed flag slots (2 u64 each); [192..200): ctl {S, k0};
// [4096 .. 4096+B*9408): W area (per elem: 48 rows x 12 float4 + 48 cneg);
// [zoff ..): z checkpoints for even k, 2 MB per slot.
#define WS_CTL_OFF 192
#define WS_W_OFF   4096
#define W_STRIDE_F 2352          // floats per element: 2304 row data + 48 cneg

__device__ __forceinline__ float bcastf(float v, int l) {
    return __int_as_float(__builtin_amdgcn_readlane(__float_as_int(v), l));
}
template <int PAT>
__device__ __forceinline__ float swz(float v) {
    return __int_as_float(__builtin_amdgcn_ds_swizzle(__float_as_int(v), PAT));
}
#define SWZ_XOR16 0x401F   // src = lane ^ 16

// One Davis-Yin step in the folded 48-MAC form.
__device__ __forceinline__ float dys_step(float z, const float* __restrict__ W,
                                          float cneg, float un, float nun,
                                          float sgn, float sgn0, int lane) {
    float z16 = swz<SWZ_XOR16>(z);
    float x   = fmaxf(z, 0.f);
    float x16 = fmaxf(z16, 0.f);
    float t1  = x - x16;
    float s   = (t1 - (z - z16)) + un;          // lanes 0-15 valid
    float h   = fmaf(2.f, x, -z);               // lanes 32-63 valid
    float ee  = fmaf(sgn0, t1, nun);            // lanes 0-31: e[lane&15]

    float a0 = cneg, a1 = 0.f, a2 = 0.f, a3 = 0.f;
    #pragma unroll
    for (int m = 0; m < 16; m += 4) {
        a0 = fmaf(W[m],     bcastf(s, m),     a0);
        a1 = fmaf(W[m + 1], bcastf(s, m + 1), a1);
        a2 = fmaf(W[m + 2], bcastf(s, m + 2), a2);
        a3 = fmaf(W[m + 3], bcastf(s, m + 3), a3);
    }
    #pragma unroll
    for (int m = 0; m < 32; m += 4) {
        a0 = fmaf(W[16 + m], bcastf(h, 32 + m), a0);
        a1 = fmaf(W[17 + m], bcastf(h, 33 + m), a1);
        a2 = fmaf(W[18 + m], bcastf(h, 34 + m), a2);
        a3 = fmaf(W[19 + m], bcastf(h, 35 + m), a3);
    }
    float acc = (a0 + a1) + (a2 + a3);          // lanes 0-31: At.w ; 32-63: w
    float t   = (lane < 32) ? fmaf(0.5f, ee, acc) : acc;
    return fmaf(sgn, t, x);
}

__device__ __forceinline__ void load_W(const float* __restrict__ eb, int lane,
                                       float* __restrict__ W, float* cneg) {
    const int col16 = lane & 15;
    const int R = (lane < 32) ? col16 : (lane - 16);   // storage row index
    const float4* Wv = (const float4*)eb;
    #pragma unroll
    for (int q = 0; q < 12; ++q) {
        float4 v = Wv[q * 48 + R];
        W[4*q] = v.x; W[4*q+1] = v.y; W[4*q+2] = v.z; W[4*q+3] = v.w;
    }
    *cneg = eb[2304 + R];
}

// ---------------- setup: build W rows + per-row constant, store to ws ----------------
__global__ __launch_bounds__(256) void dys_setup(
    const float* __restrict__ Amat,      // (B,32,16)
    const float* __restrict__ bvec,      // (B,32)
    float*       __restrict__ wws,
    int B)
{
    const int tid   = threadIdx.x;
    const int lane  = tid & 63;
    const int wib   = tid >> 6;
    const int elem  = blockIdx.x * WPB + wib;
    const int row32 = lane & 31;
    const int col16 = lane & 15;

    __shared__ __align__(16) float ldsT[WPB][32 * 17];
    float* T = ldsT[wib];      // wave-private; lgkmcnt ordering, no __syncthreads

    const float* Ab = Amat + (size_t)elem * 512 + (size_t)row32 * 16;
    float A_row[16];
    {
        float4 a0 = ((const float4*)Ab)[0];
        float4 a1 = ((const float4*)Ab)[1];
        float4 a2 = ((const float4*)Ab)[2];
        float4 a3 = ((const float4*)Ab)[3];
        A_row[0]=a0.x;  A_row[1]=a0.y;  A_row[2]=a0.z;  A_row[3]=a0.w;
        A_row[4]=a1.x;  A_row[5]=a1.y;  A_row[6]=a1.z;  A_row[7]=a1.w;
        A_row[8]=a2.x;  A_row[9]=a2.y;  A_row[10]=a2.z; A_row[11]=a2.w;
        A_row[12]=a3.x; A_row[13]=a3.y; A_row[14]=a3.z; A_row[15]=a3.w;
    }
    if (lane < 32) {
        #pragma unroll
        for (int k = 0; k < 16; ++k) T[row32 * 17 + k] = A_row[k];
    }
    const float bv = bvec[(size_t)elem * 32 + row32];

    // W rows: lanes 0-31 (i=col16): [AtQA_i | AtQ_i]; lanes 32-63 (j=lane-32): [QA_j | Q_j]
    float W[48];

    // N = 2*A*A^T + I, row (lane&31)
    {
        float A2[16];
        #pragma unroll
        for (int k = 0; k < 16; ++k) A2[k] = A_row[k] + A_row[k];
        #pragma unroll
        for (int j = 0; j < 32; ++j) {
            float acc = (row32 == j) ? 1.f : 0.f;
            #pragma unroll
            for (int k = 0; k < 16; ++k)
                acc = fmaf(A2[k], bcastf(A_row[k], j), acc);
            W[16 + j] = acc;
        }
    }

    // in-place Gauss-Jordan: W[16..47] -> Q = N^-1 row (lane&31)
    #pragma unroll
    for (int p = 0; p < 32; ++p) {
        float piv = bcastf(W[16 + p], p);
        float d = __builtin_amdgcn_rcpf(piv);
        d = d * (2.f - piv * d);
        float g = W[16 + p] * d;
        g = (row32 == p) ? (1.f - d) : g;
        float negg = -g;
        #pragma unroll
        for (int j = 0; j < 32; ++j) {
            if (j == p) continue;
            float spj = bcastf(W[16 + j], p);
            W[16 + j] = fmaf(negg, spj, W[16 + j]);
        }
        W[16 + p] = (row32 == p) ? d : negg;
    }

    // QA row (lane&31) into W[0..15]
    #pragma unroll
    for (int k = 0; k < 16; ++k) W[k] = 0.f;
    #pragma unroll
    for (int m = 0; m < 32; ++m) {
        float q = W[16 + m];
        #pragma unroll
        for (int k = 0; k < 16; ++k)
            W[k] = fmaf(q, bcastf(A_row[k], m), W[k]);
    }

    // lanes 0-31: AtQA row i (A staged in T, QA row broadcasts)
    float tq[16];
    #pragma unroll
    for (int k = 0; k < 16; ++k) tq[k] = 0.f;
    #pragma unroll
    for (int m = 0; m < 32; ++m) {
        float a_mi = T[m * 17 + col16];
        #pragma unroll
        for (int k = 0; k < 16; ++k)
            tq[k] = fmaf(a_mi, bcastf(W[k], m), tq[k]);
    }

    if (lane < 32) {
        #pragma unroll
        for (int k = 0; k < 16; ++k) T[row32 * 17 + k] = W[k];   // stage QA rows
    }
    if (lane < 32) {
        #pragma unroll
        for (int m = 0; m < 32; ++m) W[16 + m] = T[m * 17 + col16];  // AtQ[i][m]
        #pragma unroll
        for (int k = 0; k < 16; ++k) W[k] = tq[k];                   // AtQA row i
    }

    // per-row constant c = (lanes<32 ? AtQ.b : Q.b); store -c
    float cneg;
    {
        float c0 = 0.f, c1 = 0.f;
        #pragma unroll
        for (int m = 0; m < 32; m += 2) {
            c0 = fmaf(W[16 + m], bcastf(bv, m),     c0);
            c1 = fmaf(W[17 + m], bcastf(bv, m + 1), c1);
        }
        cneg = -(c0 + c1);
    }

    // ---- store: rows 0-15 from lanes 0-15, rows 16-47 from lanes 32-63 ----
    float* eb = wws + (size_t)elem * W_STRIDE_F;
    if (lane < 16 || lane >= 32) {
        const int R = (lane < 16) ? lane : (lane - 16);
        float4* dst = (float4*)eb;
        #pragma unroll
        for (int q = 0; q < 12; ++q) {
            float4 v;
            v.x = W[4*q]; v.y = W[4*q+1]; v.z = W[4*q+2]; v.w = W[4*q+3];
            dst[q * 48 + R] = v;
        }
        eb[2304 + R] = cneg;
    }
}

// ---------------- loop: 100 steps, residual masks + even-k checkpoints ----------------
__global__ __launch_bounds__(256) void dys_loop(
    const float* __restrict__ u_nom,
    const int*   __restrict__ mi_ptr,
    const float* __restrict__ wws,
    unsigned long long* __restrict__ flags,
    float*       __restrict__ zstore,
    int zcap, int B)
{
    const int tid  = threadIdx.x;
    const int lane = tid & 63;
    const int wib  = tid >> 6;
    const int elem = blockIdx.x * WPB + wib;
    const int col16 = lane & 15;

    float W[48], cneg;
    load_W(wws + (size_t)elem * W_STRIDE_F, lane, W, &cneg);

    const float un   = u_nom[(size_t)elem * 16 + col16];
    const float nun  = -un;
    const float sgn  = (lane >= 16 && lane < 32) ? 1.f : -1.f;
    const float sgn0 = (lane & 16) ? -1.f : 1.f;

    const int mi = *mi_ptr;
    const size_t zstride = (size_t)B * 64;
    const size_t zidx = (size_t)elem * 64 + lane;

    float z = 0.f;
    unsigned long long m0 = 0ull, m1 = 0ull, b0 = 1ull, b1 = 0ull;

    for (int k = 1; k <= mi; ++k) {
        float znew = dys_step(z, W, cneg, un, nun, sgn, sgn0, lane);

        unsigned long long cy = b0 >> 63;
        b0 <<= 1; b1 = (b1 << 1) | cy;              // b = 1 << k (uniform, SALU)
        unsigned long long any = __ballot(fabsf(znew - z) >= TOL);
        if (any) { m0 |= b0; m1 |= b1; }

        if (!(k & 1)) {                             // checkpoint even k
            int slot = k >> 1;                      // >= 1
            if (slot <= zcap)
                zstore[(size_t)(slot - 1) * zstride + zidx] = znew;
        }
        z = znew;
    }

    if (lane == 0) {
        int slot = blockIdx.x & 7;
        atomicOr(flags + 2 * slot,     m0);
        atomicOr(flags + 2 * slot + 1, m1);
    }
}

// S = (first k in [1,mi) with global residual < TOL) + 1, else mi. k0 = even start.
__global__ void dys_reduce(const int* __restrict__ mi_ptr,
                           const unsigned long long* __restrict__ flags,
                           int zcap, int* __restrict__ ctl)
{
    if (threadIdx.x != 0) return;
    unsigned long long m0 = 0ull, m1 = 0ull;
    for (int s = 0; s < 8; ++s) { m0 |= flags[2*s]; m1 |= flags[2*s+1]; }
    int mi = *mi_ptr;
    int S = mi;
    for (int k = 1; k < mi && k < 128; ++k) {
        unsigned long long bit = (k < 64) ? ((m0 >> k) & 1ull)
                                          : ((m1 >> (k - 64)) & 1ull);
        if (!bit) { S = k + 1; break; }
    }
    if (S < 1) S = 1;
    int k0 = S & ~1;                    // largest even <= S
    int kmax = 2 * zcap;
    if (k0 > kmax) k0 = kmax;
    ctl[0] = S;
    ctl[1] = k0;
}

// ---------------- finisher: resume from checkpoint k0, run S-k0 steps, emit ----------------
__global__ __launch_bounds__(256) void dys_finish(
    const float* __restrict__ u_nom,
    const float* __restrict__ wws,
    const int*   __restrict__ ctl,
    const float* __restrict__ zstore,
    float*       __restrict__ out,
    int B)
{
    const int tid  = threadIdx.x;
    const int lane = tid & 63;
    const int wib  = tid >> 6;
    const int elem = blockIdx.x * WPB + wib;
    const int col16 = lane & 15;

    const int S  = ctl[0];
    const int k0 = ctl[1];
    const size_t zidx = (size_t)elem * 64 + lane;

    float z = 0.f;
    if (k0 > 0)
        z = zstore[(size_t)(k0 / 2 - 1) * ((size_t)B * 64) + zidx];

    int rem = S - k0;
    if (rem > 0) {
        float W[48], cneg;
        load_W(wws + (size_t)elem * W_STRIDE_F, lane, W, &cneg);
        const float un   = u_nom[(size_t)elem * 16 + col16];
        const float nun  = -un;
        const float sgn  = (lane >= 16 && lane < 32) ? 1.f : -1.f;
        const float sgn0 = (lane & 16) ? -1.f : 1.f;
        for (int r = 0; r < rem; ++r)
            z = dys_step(z, W, cneg, un, nun, sgn, sgn0, lane);
    }

    float z16b = swz<SWZ_XOR16>(z);
    if (lane < 16) out[(size_t)elem * 16 + lane] = z - z16b;   // u_star
    out[(size_t)B * 16 + zidx] = z;                             // z_star
}

extern "C" void kernel_launch(void* const* d_in, const int* in_sizes, int n_in,
                              void* d_out, int out_size, void* d_ws, size_t ws_size,
                              hipStream_t stream) {
    (void)n_in; (void)out_size;
    const float* u_nom = (const float*)d_in[0];
    const float* Amat  = (const float*)d_in[1];
    const float* bvec  = (const float*)d_in[2];
    const int*   mi    = (const int*)d_in[3];

    const int B = in_sizes[0] / 16;                  // 8192

    unsigned long long* flags = (unsigned long long*)d_ws;
    int* ctl = (int*)((char*)d_ws + WS_CTL_OFF);
    float* wws = (float*)((char*)d_ws + WS_W_OFF);

    const size_t wbytes = (size_t)B * W_STRIDE_F * sizeof(float);   // ~77 MB
    const size_t zoff = WS_W_OFF + wbytes;
    float* zstore = (float*)((char*)d_ws + zoff);

    const size_t stepBytes = (size_t)B * 64 * sizeof(float);        // 2 MB
    int zcap = 0;
    if (ws_size > zoff + stepBytes)
        zcap = (int)((ws_size - zoff) / stepBytes);
    if (zcap > 63) zcap = 63;                        // masks cover k < 128

    hipMemsetAsync(d_ws, 0, 256, stream);            // flags + ctl

    const int blocks = B / WPB;
    dys_setup <<<blocks, 64 * WPB, 0, stream>>>(Amat, bvec, wws, B);
    dys_loop  <<<blocks, 64 * WPB, 0, stream>>>(u_nom, mi, wws, flags, zstore, zcap, B);
    dys_reduce<<<1, 64, 0, stream>>>(mi, flags, zcap, ctl);
    dys_finish<<<blocks, 64 * WPB, 0, stream>>>(u_nom, wws, ctl, zstore,
                                                (float*)d_out, B);
}